// Round 7
// baseline (303.581 us; speedup 1.0000x reference)
//
#include <hip/hip_runtime.h>

// DerivativeRBF: X(512,16), X2(512,16), uls(16), uvar(1) ->
//   K(512,512) | grad_K(8192,512) | hess_K(8192,8192) concat in d_out.
// 286 MB output, 64 KB input: write-BW problem. History:
//  R3 nt-scatter 289us | R4 plain-scatter 293us | R6 per-block-linear 300us
//  -> kernel ~110us (2.6 TB/s) invariant; poison fill on same buffer: 6.2 TB/s.
// Theory: cross-block write-stream interleave thrashes DRAM rows. The fill
// wins via ONE ~1MB moving window (grid-stride). R7: 256 persistent blocks
// (1/CU) sweep output in lockstep -> 8MB moving window; raw s_barrier with
// lgkmcnt-only (no vmcnt(0) drain) so stores free-run like the fill's.

#define NN 512
#define DD 16
#define NDD 8192
#define GOFF (NN * NN)                 // grad_K offset: 262144 floats
#define HOFF (NN * NN + NDD * NN)      // hess_K offset: 4456448 floats
#define GRID 256
#define TPB 1024

typedef float fv4 __attribute__((ext_vector_type(4)));

__device__ __forceinline__ float softplus_f(float x) {
    return fmaxf(x, 0.0f) + log1pf(expf(-fabsf(x)));   // stable, = jax.nn.softplus
}

__device__ __forceinline__ void load_row16(const float* __restrict__ p, float (&r)[DD]) {
    const fv4* p4 = (const fv4*)p;
    #pragma unroll
    for (int c = 0; c < 4; ++c) {
        fv4 v = p4[c];
        r[c*4+0] = v.x; r[c*4+1] = v.y; r[c*4+2] = v.z; r[c*4+3] = v.w;
    }
}

// barrier ordering LDS only: do NOT drain the global-store queue (vmcnt).
__device__ __forceinline__ void lds_barrier() {
    asm volatile("s_waitcnt lgkmcnt(0)" ::: "memory");
    __builtin_amdgcn_s_barrier();
}

__global__ __launch_bounds__(TPB, 4) void drbf_kernel(
    const float* __restrict__ X, const float* __restrict__ X2,
    const float* __restrict__ uls, const float* __restrict__ uvar,
    float* __restrict__ out)
{
    __shared__ float s_il2[DD];    // 1/l^2
    __shared__ float s_h2[DD];     // 0.5/l^2
    __shared__ float s_var;
    __shared__ float sS[DD][NN];   // s_d(i, j) for current row (32 KB)
    __shared__ float ta[NN];       // -0.25*k*s_a
    __shared__ float kk[NN];       // k(i, j)

    const int t  = threadIdx.x;
    const int bx = blockIdx.x;
    if (t < DD) {
        float ls = softplus_f(uls[t]);
        float i2 = 1.0f / (ls * ls);
        s_il2[t] = i2;
        s_h2[t]  = 0.5f * i2;
    }
    if (t == DD) s_var = softplus_f(uvar[0]);
    __syncthreads();
    const float var = s_var;

    // ---- hess_K: 8192 rows, grid-stride so iter k writes rows [k*256, k*256+255]
    // (one 8 MB moving window across the whole GPU).
    for (int k = 0; k < 32; ++k) {
        const int u = k * GRID + bx;     // output row index = a*512 + i
        const int a = u >> 9;
        const int i = u & 511;

        if (t < NN) {                    // phase 1: thread t handles col j = t
            float xi[DD], xj[DD];
            load_row16(X + i * DD, xi);  // lane-uniform
            load_row16(X + t * DD, xj);
            float sq = 0.f, sa = 0.f;
            #pragma unroll
            for (int d = 0; d < DD; ++d) {
                float dif = xi[d] - xj[d];
                float s   = dif * s_il2[d];
                sq += s * dif;
                if (d == a) sa = s;      // uniform cond -> cndmask
                sS[d][t] = s;
            }
            float kv = var * expf(-0.25f * sq);
            kk[t] = kv;
            ta[t] = -0.25f * kv * sa;
        }
        lds_barrier();

        // phase 2: stream the 32 KB row out; fv4 per lane, 2 stores/thread.
        const float h2a = s_h2[a];
        fv4* row = (fv4*)(out + HOFF + (size_t)u * NDD);
        #pragma unroll
        for (int r = 0; r < 2; ++r) {
            int c4 = r * TPB + t;        // fv4 index in row (0..2047)
            int b  = c4 >> 7;            // col block 0..15
            int j4 = c4 & 127;
            fv4 sB = ((const fv4*)&sS[b][0])[j4];  // stride-16B: 2-way free
            fv4 tv = ((const fv4*)ta)[j4];
            fv4 kv = ((const fv4*)kk)[j4];
            float dm = (b == a) ? h2a : 0.0f;
            row[c4] = tv * sB + kv * dm;
        }
        lds_barrier();                   // protect sS before next phase 1
    }

    // ---- grad_K: 512 units of 16 rows (32 KB linear each), 2 per block.
    {
        float x2j[DD];
        load_row16(X2 + (t & 511) * DD, x2j);   // this thread's column row
        const int half = t >> 9;                 // wave-uniform
        #pragma unroll
        for (int g = 0; g < 2; ++g) {
            const int u2   = g * GRID + bx;      // 0..511
            const int dblk = u2 >> 5;
            const int n0   = (u2 & 31) * 16;
            #pragma unroll
            for (int r = 0; r < 8; ++r) {
                const int n = n0 + half * 8 + r;
                float xn[DD];
                load_row16(X + n * DD, xn);      // lane-uniform
                float sq = 0.f, sd = 0.f;
                #pragma unroll
                for (int d = 0; d < DD; ++d) {
                    float dif = xn[d] - x2j[d];
                    float s   = dif * s_il2[d];
                    sq += s * dif;
                    if (d == dblk) sd = s;
                }
                float kv = var * expf(-0.25f * sq);
                out[GOFF + (size_t)(dblk * NN + n) * NN + (t & 511)] = -0.5f * sd * kv;
            }
        }
    }

    // ---- K: 8 units of 16 rows on blocks 0..7.
    if (bx < 8) {
        float x2j[DD];
        load_row16(X2 + (t & 511) * DD, x2j);
        const int half = t >> 9;
        const int n0 = bx * 16;
        #pragma unroll
        for (int r = 0; r < 8; ++r) {
            const int n = n0 + half * 8 + r;
            float xn[DD];
            load_row16(X + n * DD, xn);
            float sq = 0.f;
            #pragma unroll
            for (int d = 0; d < DD; ++d) {
                float dif = xn[d] - x2j[d];
                sq += dif * dif * s_il2[d];
            }
            out[(size_t)n * NN + (t & 511)] = var * expf(-0.25f * sq);
        }
    }
}

extern "C" void kernel_launch(void* const* d_in, const int* in_sizes, int n_in,
                              void* d_out, int out_size, void* d_ws, size_t ws_size,
                              hipStream_t stream) {
    const float* X    = (const float*)d_in[0];
    const float* X2   = (const float*)d_in[1];
    const float* uls  = (const float*)d_in[2];
    const float* uvar = (const float*)d_in[3];
    float* out = (float*)d_out;
    // 256 blocks x 1024 threads: 1 block/CU, sweeping write window.
    drbf_kernel<<<dim3(GRID), dim3(TPB), 0, stream>>>(X, X2, uls, uvar, out);
}